// Round 3
// baseline (223.594 us; speedup 1.0000x reference)
//
#include <hip/hip_runtime.h>

// PolyRPE attention, MI355X gfx950.
// cvt/transpose -> QKV GEMM (256x256 tile, BK=32, 3-stage counted-vmcnt
// pipeline, T2 swizzle, T5 setprio) -> fused flash attention with LUT RPE ->
// proj GEMM (same pipeline, fp32 out).
//
// Dims: B=16, N=577 (pad 640), C=768, h=12, d=64, K=768, 3C=2304.

using u16 = unsigned short;
using u32 = unsigned int;

typedef __bf16 bf16x8 __attribute__((ext_vector_type(8)));
typedef float f32x4 __attribute__((ext_vector_type(4)));

__device__ inline u16 f2bf(float f) {
    u32 u = __builtin_bit_cast(u32, f);
    u32 r = u + 0x7fffu + ((u >> 16) & 1u);   // RNE
    return (u16)(r >> 16);
}
__device__ inline float bf2f(u16 x) {
    return __builtin_bit_cast(float, (u32)x << 16);
}

__device__ inline f32x4 mfma16(bf16x8 a, bf16x8 b, f32x4 c) {
    return __builtin_amdgcn_mfma_f32_16x16x32_bf16(a, b, c, 0, 0, 0);
}

__device__ inline float fexp2(float x) { return __builtin_amdgcn_exp2f(x); }

// 16-lane (DPP-row) reductions.
__device__ inline float dpp_max16(float v) {
    int x;
    x = __builtin_amdgcn_update_dpp(0, __builtin_bit_cast(int, v), 0xB1, 0xF, 0xF, true);
    v = fmaxf(v, __builtin_bit_cast(float, x));
    x = __builtin_amdgcn_update_dpp(0, __builtin_bit_cast(int, v), 0x4E, 0xF, 0xF, true);
    v = fmaxf(v, __builtin_bit_cast(float, x));
    x = __builtin_amdgcn_update_dpp(0, __builtin_bit_cast(int, v), 0x124, 0xF, 0xF, true);
    v = fmaxf(v, __builtin_bit_cast(float, x));
    x = __builtin_amdgcn_update_dpp(0, __builtin_bit_cast(int, v), 0x128, 0xF, 0xF, true);
    v = fmaxf(v, __builtin_bit_cast(float, x));
    return v;
}
__device__ inline float dpp_sum16(float v) {
    int x;
    x = __builtin_amdgcn_update_dpp(0, __builtin_bit_cast(int, v), 0xB1, 0xF, 0xF, true);
    v += __builtin_bit_cast(float, x);
    x = __builtin_amdgcn_update_dpp(0, __builtin_bit_cast(int, v), 0x4E, 0xF, 0xF, true);
    v += __builtin_bit_cast(float, x);
    x = __builtin_amdgcn_update_dpp(0, __builtin_bit_cast(int, v), 0x124, 0xF, 0xF, true);
    v += __builtin_bit_cast(float, x);
    x = __builtin_amdgcn_update_dpp(0, __builtin_bit_cast(int, v), 0x128, 0xF, 0xF, true);
    v += __builtin_bit_cast(float, x);
    return v;
}

#define GLOAD_LDS16(g, l)                                                          \
    __builtin_amdgcn_global_load_lds((const __attribute__((address_space(1))) u32*)(g), \
                                     (__attribute__((address_space(3))) u32*)(l), 16, 0, 0)

#define BAR()    asm volatile("s_barrier" ::: "memory")
#define WAITV4() asm volatile("s_waitcnt vmcnt(4)" ::: "memory")
#define WAITV0() asm volatile("s_waitcnt vmcnt(0)" ::: "memory")

// ---------------- fp32 -> bf16, same layout (vectorized x4) ----------------
__global__ void k_cvt(const float* __restrict__ in, u16* __restrict__ out, int n4) {
    int i = blockIdx.x * blockDim.x + threadIdx.x;
    const int stride = gridDim.x * blockDim.x;
    for (; i < n4; i += stride) {
        float4 v = ((const float4*)in)[i];
        ushort4 o;
        o.x = f2bf(v.x); o.y = f2bf(v.y); o.z = f2bf(v.z); o.w = f2bf(v.w);
        ((ushort4*)out)[i] = o;
    }
}

// ---------------- fp32 [R][C] -> bf16 [C][R] ----------------
__global__ void k_tr(const float* __restrict__ in, u16* __restrict__ out, int R, int C) {
    int i = blockIdx.x * blockDim.x + threadIdx.x;
    const int total = R * C;
    const int stride = gridDim.x * blockDim.x;
    for (; i < total; i += stride) {
        int r = i / C, c = i - r * C;
        out[(size_t)c * R + r] = f2bf(in[i]);
    }
}

// ---------------- pipelined GEMM helpers ----------------
// LDS tile layout per buffer: A[256][32] then B[256][32] bf16, with 16B-slot
// swizzle: slot' = slot ^ ((row>>1)&3)  (involution, applied on stage-source
// and on ds_read addr; conflict-free for the 16-row frag read pattern).
__device__ inline void stage_pair(const u16* __restrict__ Ga, const u16* __restrict__ Gb,
                                  u16* ldsA, u16* ldsB, int cc, int l) {
    const int r = cc * 16 + (l >> 2);                 // 0..255 tile row
    const int s = ((l & 3) ^ ((r >> 1) & 3)) * 8;     // swizzled src slot (elems)
    GLOAD_LDS16(Ga + (size_t)r * 768 + s, ldsA + cc * 512);
    GLOAD_LDS16(Gb + (size_t)r * 768 + s, ldsB + cc * 512);
}

__device__ inline bf16x8 ldfrag(const u16* base, int row, int slot) {
    return *(const bf16x8*)(base + row * 32 + ((slot ^ ((row >> 1) & 3)) * 8));
}

// GEMM: C[M x N] = A[M x 768] * Bw^T, Bw is [N][768] bf16.
// 256x256 tile, BK=32, 8 waves (2Mx4N, per-wave 128x64), 3-stage pipeline.
// MODE 0: QKV scatter (N=2304) -> Q/K [bh][640][64], Vt [bh][64][640]
// MODE 1: proj (N=768) -> fp32 out + bias
template <int MODE>
__launch_bounds__(512, 2)
__global__ void k_gemm2(const u16* __restrict__ A, const u16* __restrict__ Bw,
                        u16* __restrict__ q_out, u16* __restrict__ k_out,
                        u16* __restrict__ v_out,
                        float* __restrict__ f_out, const float* __restrict__ bias) {
    extern __shared__ u16 lds[];              // 3 bufs x (8192 A + 8192 B)
    constexpr int NT = 24;                    // 768 / 32
    const int mbase = blockIdx.x * 256;
    const int nbase = blockIdx.y * 256;
    const int tid = threadIdx.x;
    const int l = tid & 63, w = tid >> 6;
    const int lr = l & 15, lg = l >> 4;
    const int wm = w >> 2, wn = w & 3;        // 2 x 4 waves
    const u16* Ag = A + (size_t)mbase * 768;
    const u16* Bg = Bw + (size_t)nbase * 768;

    f32x4 acc[8][4] = {};

    // prologue: stage K-tiles 0 -> buf0, 1 -> buf1 (8 loads/thread)
    stage_pair(Ag, Bg, lds, lds + 8192, w, l);
    stage_pair(Ag, Bg, lds, lds + 8192, w + 8, l);
    stage_pair(Ag + 32, Bg + 32, lds + 16384, lds + 24576, w, l);
    stage_pair(Ag + 32, Bg + 32, lds + 16384, lds + 24576, w + 8, l);
    WAITV4();          // tile 0 resident (tile 1's 4 loads stay in flight)
    BAR();

    for (int kt = 0; kt < NT; ++kt) {
        const int p = kt % 3;
        const u16* Ab = lds + p * 16384;
        const u16* Bb = Ab + 8192;
        const int pre = (kt + 2) % 3;
        u16* Pa = lds + pre * 16384;
        u16* Pb = Pa + 8192;
        const u16* Ga = Ag + (size_t)(kt + 2) * 32;
        const u16* Gb = Bg + (size_t)(kt + 2) * 32;
        const bool more = (kt + 2) < NT;

        bf16x8 bfr[4], afr[4];
        // ---- phase 0: B frags + A frags mi 0..3; stage 2 chunks of t+2
#pragma unroll
        for (int nj = 0; nj < 4; ++nj)
            bfr[nj] = ldfrag(Bb, wn * 64 + nj * 16 + lr, lg);
#pragma unroll
        for (int mi = 0; mi < 4; ++mi)
            afr[mi] = ldfrag(Ab, wm * 128 + mi * 16 + lr, lg);
        if (more) stage_pair(Ga, Gb, Pa, Pb, w, l);
        BAR();
        __builtin_amdgcn_s_setprio(1);
#pragma unroll
        for (int mi = 0; mi < 4; ++mi)
#pragma unroll
            for (int nj = 0; nj < 4; ++nj)
                acc[mi][nj] = mfma16(afr[mi], bfr[nj], acc[mi][nj]);
        __builtin_amdgcn_s_setprio(0);

        // ---- phase 1: A frags mi 4..7; stage 2 more chunks of t+2
#pragma unroll
        for (int mi = 0; mi < 4; ++mi)
            afr[mi] = ldfrag(Ab, wm * 128 + (mi + 4) * 16 + lr, lg);
        if (more) stage_pair(Ga, Gb, Pa, Pb, w + 8, l);
        BAR();
        __builtin_amdgcn_s_setprio(1);
#pragma unroll
        for (int mi = 0; mi < 4; ++mi)
#pragma unroll
            for (int nj = 0; nj < 4; ++nj)
                acc[mi + 4][nj] = mfma16(afr[mi], bfr[nj], acc[mi + 4][nj]);
        __builtin_amdgcn_s_setprio(0);

        // ---- iteration end: tile kt+1 must be resident before next read
        if (kt + 1 < NT) {
            if (more) { WAITV4(); } else { WAITV0(); }
            BAR();
        }
    }

    // ---- epilogue
    if (MODE == 0) {
        const int by = blockIdx.y;            // 0..8, 3 tiles per q/k/v
        const int ttype = by / 3;
        const int rem0 = (by % 3) * 256 + wn * 64;
#pragma unroll
        for (int nj = 0; nj < 4; ++nj) {
            const int rem = rem0 + nj * 16 + lr;
            const int hh = rem >> 6, dd = rem & 63;
#pragma unroll
            for (int mi = 0; mi < 8; ++mi) {
#pragma unroll
                for (int r = 0; r < 4; ++r) {
                    const int row = mbase + wm * 128 + mi * 16 + 4 * lg + r;
                    if (row < 9232) {
                        const int bb = row / 577;
                        const int nn = row - bb * 577;
                        const size_t bh = (size_t)bb * 12 + hh;
                        const u16 val = f2bf(acc[mi][nj][r]);
                        if (ttype == 0)      q_out[(bh * 640 + nn) * 64 + dd] = val;
                        else if (ttype == 1) k_out[(bh * 640 + nn) * 64 + dd] = val;
                        else                 v_out[(bh * 64 + dd) * 640 + nn] = val;
                    }
                }
            }
        }
    } else {
#pragma unroll
        for (int nj = 0; nj < 4; ++nj) {
            const int col = nbase + wn * 64 + nj * 16 + lr;
            const float bv = bias[col];
#pragma unroll
            for (int mi = 0; mi < 8; ++mi) {
#pragma unroll
                for (int r = 0; r < 4; ++r) {
                    const int row = mbase + wm * 128 + mi * 16 + 4 * lg + r;
                    if (row < 9232)
                        f_out[(size_t)row * 768 + col] = acc[mi][nj][r] + bv;
                }
            }
        }
    }
}

// ---------------- fused attention (q rows 0..575) ----------------
__launch_bounds__(256)
__global__ void k_attn(const u16* __restrict__ Qg, const u16* __restrict__ Kg,
                       const u16* __restrict__ Vtg, const float* __restrict__ coef,
                       u16* __restrict__ Og) {
    const int bh = blockIdx.x;          // 0..191
    const int qt = blockIdx.y;          // 0..8
    const int b = bh / 12, h = bh - b * 12;
    const int t = threadIdx.x;
    const int lane = t & 63, w = t >> 6;
    const int lr = lane & 15, lg = lane >> 4;
    __shared__ alignas(16) u16 Klds[64 * 64];
    __shared__ alignas(16) u16 Vlds[64 * 64];   // [d][key]
    __shared__ alignas(16) u16 Plds[4][16 * 72];
    __shared__ float lut[256];

    // LUT: poly(dist)*log2e for dist<=46, else 0 (CLS coords land in 47..255)
    {
        const float l2e = 1.4426950408889634f;
        const float c0 = coef[h * 4 + 0] * l2e, c1 = coef[h * 4 + 1] * l2e,
                    c2 = coef[h * 4 + 2] * l2e, c3 = coef[h * 4 + 3] * l2e;
        const float d = (float)t;
        lut[t] = (t <= 46) ? (((c3 * d + c2) * d + c1) * d + c0) : 0.f;
    }

    const int qrow0 = qt * 64 + w * 16;
    const u16* qp = Qg + ((size_t)bh * 640 + qrow0 + lr) * 64;
    const bf16x8 qa0 = *(const bf16x8*)(qp + lg * 8);
    const bf16x8 qa1 = *(const bf16x8*)(qp + 32 + lg * 8);

    float gi[4], gj[4];
#pragma unroll
    for (int r = 0; r < 4; ++r) {
        const int n = qrow0 + 4 * lg + r;
        if (n == 0) { gi[r] = 100.f; gj[r] = 0.f; }
        else {
            const int nm1 = n - 1;
            const int qi = nm1 / 24;
            gi[r] = (float)qi;
            gj[r] = (float)(nm1 - qi * 24);
        }
    }

    float M[4], L[4];
#pragma unroll
    for (int r = 0; r < 4; ++r) { M[r] = -3e38f; L[r] = 0.f; }
    f32x4 acco[4] = {};
    const float scale2 = 0.125f * 1.4426950408889634f;
    const int ch0 = ((lg ^ (lr & 7))) * 8;      // swizzled chunk (u16 offset)

    for (int kt = 0; kt < 10; ++kt) {
        const bool full = (kt < 9);
        const u16* Ks = Kg + ((size_t)bh * 640 + kt * 64) * 64;
        const u16* Vs = Vtg + (size_t)bh * 64 * 640 + kt * 64;
        // stage with inverse-swizzled SOURCE, linear LDS dest
#pragma unroll
        for (int call = 0; call < 2; ++call) {
            const int c = call * 256 + t;
            const int row = c >> 3;
            const int sc = ((c & 7) ^ (row & 7)) * 8;
            GLOAD_LDS16(Ks + (size_t)row * 64 + sc,
                        Klds + (size_t)(call * 256 + w * 64) * 8);
            GLOAD_LDS16(Vs + (size_t)row * 640 + sc,
                        Vlds + (size_t)(call * 256 + w * 64) * 8);
        }
        __syncthreads();

        // S = Q K^T
        f32x4 sac[4];
#pragma unroll
        for (int cb = 0; cb < 4; ++cb) {
            if (full || cb == 0) {
                const int row = cb * 16 + lr;
                const bf16x8 kb0 = *(const bf16x8*)(Klds + row * 64 + ch0);
                const bf16x8 kb1 = *(const bf16x8*)(Klds + row * 64 + (ch0 ^ 32));
                f32x4 z = {};
                z = mfma16(qa0, kb0, z);
                sac[cb] = mfma16(qa1, kb1, z);
            }
        }

        float s[4][4], tm[4];
#pragma unroll
        for (int r = 0; r < 4; ++r) tm[r] = -3e38f;
#pragma unroll
        for (int cb = 0; cb < 4; ++cb) {
            if (full || cb == 0) {
                const int m = kt * 64 + cb * 16 + lr;
                float ci, cj;
                if (m == 0) { ci = 200.f; cj = 0.f; }
                else {
                    const int mm1 = m - 1;
                    const int pi = mm1 / 24;
                    ci = (float)pi;
                    cj = (float)(mm1 - pi * 24);
                }
#pragma unroll
                for (int r = 0; r < 4; ++r) {
                    const float df = fabsf(gi[r] - ci) + fabsf(gj[r] - cj);
                    const int idx = (int)df;
                    float v = fmaf(sac[cb][r], scale2, lut[idx]);
                    if (!full) v = (lr == 0) ? v : -1e30f;   // pad keys on tail tile
                    s[cb][r] = v;
                    tm[r] = fmaxf(tm[r], v);
                }
            } else {
#pragma unroll
                for (int r = 0; r < 4; ++r) s[cb][r] = -1e30f;
            }
        }
#pragma unroll
        for (int r = 0; r < 4; ++r) tm[r] = dpp_max16(tm[r]);

        // defer-max: rescale only when tile max exceeds running max + 11.5
        float over = tm[0] - M[0];
        over = fmaxf(over, tm[1] - M[1]);
        over = fmaxf(over, tm[2] - M[2]);
        over = fmaxf(over, tm[3] - M[3]);
        if (__any(over > 11.5f)) {
#pragma unroll
            for (int r = 0; r < 4; ++r) {
                const float Mn = fmaxf(M[r], tm[r]);
                const float a = fexp2(M[r] - Mn);
                L[r] *= a;
                acco[0][r] *= a; acco[1][r] *= a;
                acco[2][r] *= a; acco[3][r] *= a;
                M[r] = Mn;
            }
        }

        // p = 2^(s-M); per-lane L partials; P -> per-wave LDS (stride 72)
        u16* pw = &Plds[w][0];
#pragma unroll
        for (int cb = 0; cb < 4; ++cb)
#pragma unroll
            for (int r = 0; r < 4; ++r) {
                const float p = fexp2(s[cb][r] - M[r]);
                L[r] += p;
                pw[(4 * lg + r) * 72 + cb * 16 + lr] = f2bf(p);
            }
        const bf16x8 pa0 = *(const bf16x8*)(pw + lr * 72 + lg * 8);
        const bf16x8 pa1 = *(const bf16x8*)(pw + lr * 72 + 32 + lg * 8);
#pragma unroll
        for (int f = 0; f < 4; ++f) {
            const int vrow = f * 16 + lr;
            const bf16x8 vb0 = *(const bf16x8*)(Vlds + vrow * 64 + ch0);
            acco[f] = mfma16(pa0, vb0, acco[f]);
            if (full) {
                const bf16x8 vb1 = *(const bf16x8*)(Vlds + vrow * 64 + (ch0 ^ 32));
                acco[f] = mfma16(pa1, vb1, acco[f]);
            }
        }
        __syncthreads();
    }

    float inv[4];
#pragma unroll
    for (int r = 0; r < 4; ++r) inv[r] = __builtin_amdgcn_rcpf(dpp_sum16(L[r]));
#pragma unroll
    for (int f = 0; f < 4; ++f)
#pragma unroll
        for (int r = 0; r < 4; ++r) {
            const int n = qrow0 + 4 * lg + r;     // <= 575, always valid
            Og[((size_t)b * 577 + n) * 768 + h * 64 + f * 16 + lr] =
                f2bf(acco[f][r] * inv[r]);
        }
}

// ---------------- attention for the single leftover row n=576 ----------------
__launch_bounds__(256)
__global__ void k_attn_last(const u16* __restrict__ Qg, const u16* __restrict__ Kg,
                            const u16* __restrict__ Vtg, const float* __restrict__ coef,
                            u16* __restrict__ Og) {
    const int bh = blockIdx.x;
    const int b = bh / 12, h = bh - b * 12;
    const int t = threadIdx.x;
    const int lane = t & 63, w = t >> 6;
    __shared__ float qs[64];
    __shared__ float ps[640];
    __shared__ float red[4];
    __shared__ float opart[4][64];
    const float l2e = 1.4426950408889634f;
    const float c0 = coef[h * 4 + 0] * l2e, c1 = coef[h * 4 + 1] * l2e,
                c2 = coef[h * 4 + 2] * l2e, c3 = coef[h * 4 + 3] * l2e;
    const float scale2 = 0.125f * l2e;

    if (t < 64) qs[t] = bf2f(Qg[((size_t)bh * 640 + 576) * 64 + t]);
    __syncthreads();

    float sv[3];
#pragma unroll
    for (int u = 0; u < 3; ++u) {
        const int k = t + u * 256;
        float s = -3e38f;
        if (k < 577) {
            const u16* kp = Kg + ((size_t)bh * 640 + k) * 64;
            float acc = 0.f;
            for (int j = 0; j < 64; ++j) acc += qs[j] * bf2f(kp[j]);
            float rv = 0.f;
            if (k >= 1) {
                const int km1 = k - 1;
                const int ki = km1 / 24;
                const float d = fabsf(23.f - (float)ki) + fabsf(23.f - (float)(km1 - ki * 24));
                rv = ((c3 * d + c2) * d + c1) * d + c0;
            }
            s = fmaf(acc, scale2, rv);
        }
        sv[u] = s;
    }
    float v = fmaxf(fmaxf(sv[0], sv[1]), sv[2]);
    v = fmaxf(v, __shfl_xor(v, 1));  v = fmaxf(v, __shfl_xor(v, 2));
    v = fmaxf(v, __shfl_xor(v, 4));  v = fmaxf(v, __shfl_xor(v, 8));
    v = fmaxf(v, __shfl_xor(v, 16)); v = fmaxf(v, __shfl_xor(v, 32));
    if (lane == 0) red[w] = v;
    __syncthreads();
    const float Mx = fmaxf(fmaxf(red[0], red[1]), fmaxf(red[2], red[3]));

    float lsum = 0.f;
#pragma unroll
    for (int u = 0; u < 3; ++u) {
        const int k = t + u * 256;
        const float p = (k < 577) ? fexp2(sv[u] - Mx) : 0.f;
        if (k < 640) ps[k] = p;
        lsum += p;
    }
    lsum += __shfl_xor(lsum, 1);  lsum += __shfl_xor(lsum, 2);
    lsum += __shfl_xor(lsum, 4);  lsum += __shfl_xor(lsum, 8);
    lsum += __shfl_xor(lsum, 16); lsum += __shfl_xor(lsum, 32);
    __syncthreads();
    if (lane == 0) red[w] = lsum;
    __syncthreads();
    const float Lx = red[0] + red[1] + red[2] + red[3];

    const int d = t & 63, qd = t >> 6;
    const u16* vp = Vtg + ((size_t)bh * 64 + d) * 640;
    float o = 0.f;
    for (int k = qd * 160; k < qd * 160 + 160; ++k) o += ps[k] * bf2f(vp[k]);
    opart[qd][d] = o;
    __syncthreads();
    if (t < 64) {
        const float oo = (opart[0][t] + opart[1][t] + opart[2][t] + opart[3][t]) / Lx;
        Og[((size_t)b * 577 + 576) * 768 + h * 64 + t] = f2bf(oo);
    }
}

// ---------------- launch ----------------
extern "C" void kernel_launch(void* const* d_in, const int* in_sizes, int n_in,
                              void* d_out, int out_size, void* d_ws, size_t ws_size,
                              hipStream_t stream) {
    const float* x      = (const float*)d_in[0];
    const float* W_qkv  = (const float*)d_in[1];
    const float* W_proj = (const float*)d_in[2];
    const float* b_proj = (const float*)d_in[3];
    const float* coef   = (const float*)d_in[4];
    float* out = (float*)d_out;
    char* ws = (char*)d_ws;

    u16* xb   = (u16*)(ws + 0);                        // 9232*768*2   = 14,180,352
    u16* Og   = (u16*)(ws + 14180352);                 // 9232*768*2   = 14,180,352
    u16* wqkv = (u16*)(ws + 28360704);                 // 2304*768*2   =  3,538,944
    u16* wprj = (u16*)(ws + 31899648);                 // 768*768*2    =  1,179,648
    u16* Qg   = (u16*)(ws + 33079296);                 // 192*640*64*2 = 15,728,640
    u16* Kg   = (u16*)(ws + 48807936);                 // 192*640*64*2 = 15,728,640
    u16* Vtg  = (u16*)(ws + 64536576);                 // 192*64*640*2 = 15,728,640

    hipMemsetAsync(Vtg, 0, 15728640, stream);          // pad keys -> 0

    k_cvt<<<2048, 256, 0, stream>>>(x, xb, 9232 * 768 / 4);
    k_tr<<<2048, 256, 0, stream>>>(W_qkv, wqkv, 768, 2304);
    k_tr<<<1024, 256, 0, stream>>>(W_proj, wprj, 768, 768);

    k_gemm2<0><<<dim3(37, 9), 512, 98304, stream>>>(xb, wqkv, Qg, Kg, Vtg,
                                                    nullptr, nullptr);
    k_attn<<<dim3(192, 9), 256, 0, stream>>>(Qg, Kg, Vtg, coef, Og);
    k_attn_last<<<192, 256, 0, stream>>>(Qg, Kg, Vtg, coef, Og);
    k_gemm2<1><<<dim3(37, 3), 512, 98304, stream>>>(Og, wprj, nullptr, nullptr,
                                                    nullptr, out, b_proj);
}

// Round 4
// 195.156 us; speedup vs baseline: 1.1457x; 1.1457x over previous
//
#include <hip/hip_runtime.h>

// PolyRPE attention, MI355X gfx950.
// prep (cvt+tr) -> QKV GEMM (128x128, BK=32, triple-buffered gl_lds,
// counted vmcnt(4), 1 barrier/iter, T2 swizzle) -> fused flash attention
// (reg-staged K/V double-buffer, LUT RPE, exp2, defer-max, DPP) -> proj GEMM.
//
// Dims: B=16, N=577 (pad 640), C=768, h=12, d=64, K=768, 3C=2304.

using u16 = unsigned short;
using u32 = unsigned int;

typedef __bf16 bf16x8 __attribute__((ext_vector_type(8)));
typedef float f32x4 __attribute__((ext_vector_type(4)));

__device__ inline u16 f2bf(float f) {
    u32 u = __builtin_bit_cast(u32, f);
    u32 r = u + 0x7fffu + ((u >> 16) & 1u);   // RNE
    return (u16)(r >> 16);
}
__device__ inline float bf2f(u16 x) {
    return __builtin_bit_cast(float, (u32)x << 16);
}

__device__ inline f32x4 mfma16(bf16x8 a, bf16x8 b, f32x4 c) {
    return __builtin_amdgcn_mfma_f32_16x16x32_bf16(a, b, c, 0, 0, 0);
}

__device__ inline float fexp2(float x) { return __builtin_amdgcn_exp2f(x); }

// 16-lane (DPP-row) reductions.
__device__ inline float dpp_max16(float v) {
    int x;
    x = __builtin_amdgcn_update_dpp(0, __builtin_bit_cast(int, v), 0xB1, 0xF, 0xF, true);
    v = fmaxf(v, __builtin_bit_cast(float, x));
    x = __builtin_amdgcn_update_dpp(0, __builtin_bit_cast(int, v), 0x4E, 0xF, 0xF, true);
    v = fmaxf(v, __builtin_bit_cast(float, x));
    x = __builtin_amdgcn_update_dpp(0, __builtin_bit_cast(int, v), 0x124, 0xF, 0xF, true);
    v = fmaxf(v, __builtin_bit_cast(float, x));
    x = __builtin_amdgcn_update_dpp(0, __builtin_bit_cast(int, v), 0x128, 0xF, 0xF, true);
    v = fmaxf(v, __builtin_bit_cast(float, x));
    return v;
}
__device__ inline float dpp_sum16(float v) {
    int x;
    x = __builtin_amdgcn_update_dpp(0, __builtin_bit_cast(int, v), 0xB1, 0xF, 0xF, true);
    v += __builtin_bit_cast(float, x);
    x = __builtin_amdgcn_update_dpp(0, __builtin_bit_cast(int, v), 0x4E, 0xF, 0xF, true);
    v += __builtin_bit_cast(float, x);
    x = __builtin_amdgcn_update_dpp(0, __builtin_bit_cast(int, v), 0x124, 0xF, 0xF, true);
    v += __builtin_bit_cast(float, x);
    x = __builtin_amdgcn_update_dpp(0, __builtin_bit_cast(int, v), 0x128, 0xF, 0xF, true);
    v += __builtin_bit_cast(float, x);
    return v;
}

#define GLOAD_LDS16(g, l)                                                          \
    __builtin_amdgcn_global_load_lds((const __attribute__((address_space(1))) u32*)(g), \
                                     (__attribute__((address_space(3))) u32*)(l), 16, 0, 0)

#define BAR()    asm volatile("s_barrier" ::: "memory")
#define WAITV4() asm volatile("s_waitcnt vmcnt(4)" ::: "memory")
#define WAITV0() asm volatile("s_waitcnt vmcnt(0)" ::: "memory")

// ---------------- prep: cvt x -> bf16, transpose both weights ----------------
__global__ void k_prep(const float* __restrict__ x, const float* __restrict__ Wq,
                       const float* __restrict__ Wp, u16* __restrict__ xb,
                       u16* __restrict__ wqkv, u16* __restrict__ wprj) {
    const int tid0 = blockIdx.x * blockDim.x + threadIdx.x;
    const int stride = gridDim.x * blockDim.x;
    const int n4 = 9232 * 768 / 4;
    for (int i = tid0; i < n4; i += stride) {
        float4 v = ((const float4*)x)[i];
        ushort4 o;
        o.x = f2bf(v.x); o.y = f2bf(v.y); o.z = f2bf(v.z); o.w = f2bf(v.w);
        ((ushort4*)xb)[i] = o;
    }
    for (int i = tid0; i < 768 * 2304; i += stride) {
        int r = i / 2304, c = i - r * 2304;
        wqkv[(size_t)c * 768 + r] = f2bf(Wq[i]);
    }
    for (int i = tid0; i < 768 * 768; i += stride) {
        int r = i / 768, c = i - r * 768;
        wprj[(size_t)c * 768 + r] = f2bf(Wp[i]);
    }
}

// ---------------- GEMM helpers (swizzle: chunk' = chunk ^ ((row>>1)&3)) -----
__device__ inline void stageAB(const u16* __restrict__ Ag, const u16* __restrict__ Bg,
                               u16* La, u16* Lb, int t, int w) {
#pragma unroll
    for (int c = 0; c < 2; ++c) {
        const int p = c * 256 + t;
        const int row = p >> 2, ch = p & 3;
        const int src = row * 768 + ((ch ^ ((row >> 1) & 3)) * 8);
        GLOAD_LDS16(Ag + src, La + (size_t)(c * 256 + w * 64) * 8);
        GLOAD_LDS16(Bg + src, Lb + (size_t)(c * 256 + w * 64) * 8);
    }
}
__device__ inline bf16x8 ldfrag32(const u16* base, int row, int slot) {
    return *(const bf16x8*)(base + row * 32 + ((slot ^ ((row >> 1) & 3)) * 8));
}

// GEMM: C[M x N] = A[M x 768] * Bw^T, Bw [N][768] bf16. 128x128 tile, BK=32,
// 4 waves (2x2 of 64x64), triple-buffered gl_lds pipeline, vmcnt(4).
// grid (Nblk, Mblk) so consecutive blocks share the A-strip (L2 locality).
// MODE 0: QKV scatter -> Q/K [bh][640][64], Vt [bh][64][640]; MODE 1: fp32+bias.
template <int MODE>
__launch_bounds__(256, 3)
__global__ void k_gemm(const u16* __restrict__ A, const u16* __restrict__ Bw,
                       u16* __restrict__ q_out, u16* __restrict__ k_out,
                       u16* __restrict__ v_out,
                       float* __restrict__ f_out, const float* __restrict__ bias) {
    constexpr int NT = 24;                    // 768/32
    constexpr int M = 9232;
    const int mbase = blockIdx.y * 128;
    const int nbase = blockIdx.x * 128;
    __shared__ alignas(16) u16 lds[3][2][128 * 32];   // 48 KB
    const int t = threadIdx.x;
    const int lane = t & 63, w = t >> 6;
    const int lr = lane & 15, lg = lane >> 4;
    const int wrow = (w >> 1) * 64, wcol = (w & 1) * 64;
    const u16* Ag = A + (size_t)mbase * 768;
    const u16* Bg = Bw + (size_t)nbase * 768;
    f32x4 acc[4][4] = {};

    stageAB(Ag, Bg, &lds[0][0][0], &lds[0][1][0], t, w);
    stageAB(Ag + 32, Bg + 32, &lds[1][0][0], &lds[1][1][0], t, w);
    WAITV4();           // tile 0 resident; tile 1 in flight
    BAR();

    for (int kt = 0; kt < NT; ++kt) {
        const int cb = kt % 3;
        const u16* Ab = &lds[cb][0][0];
        const u16* Bb = &lds[cb][1][0];
        const bool m2 = (kt + 2) < NT;
        if (m2) {
            const int nb = (kt + 2) % 3;
            stageAB(Ag + (kt + 2) * 32, Bg + (kt + 2) * 32,
                    &lds[nb][0][0], &lds[nb][1][0], t, w);
        }
        bf16x8 af[4], bv[4];
#pragma unroll
        for (int i = 0; i < 4; ++i)
            af[i] = ldfrag32(Ab, wrow + i * 16 + lr, lg);
#pragma unroll
        for (int j = 0; j < 4; ++j)
            bv[j] = ldfrag32(Bb, wcol + j * 16 + lr, lg);
        __builtin_amdgcn_s_setprio(1);
#pragma unroll
        for (int i = 0; i < 4; ++i)
#pragma unroll
            for (int j = 0; j < 4; ++j)
                acc[i][j] = mfma16(af[i], bv[j], acc[i][j]);
        __builtin_amdgcn_s_setprio(0);
        if (kt + 1 < NT) {
            if (m2) { WAITV4(); } else { WAITV0(); }
            BAR();
        }
    }

#pragma unroll
    for (int i = 0; i < 4; ++i) {
#pragma unroll
        for (int j = 0; j < 4; ++j) {
            const int col = nbase + wcol + j * 16 + lr;
#pragma unroll
            for (int r = 0; r < 4; ++r) {
                const int row = mbase + wrow + i * 16 + 4 * lg + r;
                if (row < M) {
                    if (MODE == 0) {
                        const int bb = row / 577;
                        const int nn = row - bb * 577;
                        const int tt = col / 768;
                        const int rem = col - tt * 768;
                        const int hh = rem >> 6, dd = rem & 63;
                        const size_t bh = (size_t)bb * 12 + hh;
                        const u16 val = f2bf(acc[i][j][r]);
                        if (tt == 0)      q_out[(bh * 640 + nn) * 64 + dd] = val;
                        else if (tt == 1) k_out[(bh * 640 + nn) * 64 + dd] = val;
                        else              v_out[(bh * 64 + dd) * 640 + nn] = val;
                    } else {
                        f_out[(size_t)row * 768 + col] = acc[i][j][r] + bias[col];
                    }
                }
            }
        }
    }
}

// ---------------- fused attention (q rows 0..575) ----------------
// K/V tiles reg-staged one tile ahead (T14), double-buffered swizzled LDS.
__launch_bounds__(256, 3)
__global__ void k_attn(const u16* __restrict__ Qg, const u16* __restrict__ Kg,
                       const u16* __restrict__ Vtg, const float* __restrict__ coef,
                       u16* __restrict__ Og) {
    const int bh = blockIdx.x;          // 0..191
    const int qt = blockIdx.y;          // 0..8
    const int b = bh / 12, h = bh - b * 12;
    const int t = threadIdx.x;
    const int lane = t & 63, w = t >> 6;
    const int lr = lane & 15, lg = lane >> 4;
    __shared__ alignas(16) u16 Kl[2][4096];
    __shared__ alignas(16) u16 Vl[2][4096];
    __shared__ alignas(16) u16 Plds[4][16 * 72];
    __shared__ float lut[256];

    {   // LUT: poly(dist)*log2e for dist<=46, else 0 (CLS coords -> 47..255)
        const float l2e = 1.4426950408889634f;
        const float c0 = coef[h * 4 + 0] * l2e, c1 = coef[h * 4 + 1] * l2e,
                    c2 = coef[h * 4 + 2] * l2e, c3 = coef[h * 4 + 3] * l2e;
        const float d = (float)t;
        lut[t] = (t <= 46) ? (((c3 * d + c2) * d + c1) * d + c0) : 0.f;
    }

    const int qrow0 = qt * 64 + w * 16;
    const u16* qp = Qg + ((size_t)bh * 640 + qrow0 + lr) * 64;
    const bf16x8 qa0 = *(const bf16x8*)(qp + lg * 8);
    const bf16x8 qa1 = *(const bf16x8*)(qp + 32 + lg * 8);

    float gi[4], gj[4];
#pragma unroll
    for (int r = 0; r < 4; ++r) {
        const int n = qrow0 + 4 * lg + r;
        if (n == 0) { gi[r] = 100.f; gj[r] = 0.f; }
        else {
            const int nm1 = n - 1;
            const int qi = nm1 / 24;
            gi[r] = (float)qi;
            gj[r] = (float)(nm1 - qi * 24);
        }
    }

    float M[4], L[4];
#pragma unroll
    for (int r = 0; r < 4; ++r) { M[r] = -3e38f; L[r] = 0.f; }
    f32x4 acco[4] = {};
    const float scale2 = 0.125f * 1.4426950408889634f;
    const int ch0 = ((lg ^ (lr & 7))) * 8;      // swizzled read chunk (elems)

    const u16* Ksb = Kg + (size_t)bh * 640 * 64;
    const u16* Vsb = Vtg + (size_t)bh * 64 * 640;
    // per-thread staging pieces: p = c*256+t -> row p>>3, chunk p&7
    const int pr0 = t >> 3, pc0 = t & 7;
    const int pr1 = (256 + t) >> 3, pc1 = (256 + t) & 7;
    const int kd0 = pr0 * 64 + ((pc0 ^ (pr0 & 7)) * 8);   // swizzled LDS elem offs
    const int kd1 = pr1 * 64 + ((pc1 ^ (pr1 & 7)) * 8);

    {   // prologue: tile 0 -> regs -> LDS buf 0
        uint4 k0 = *(const uint4*)(Ksb + pr0 * 64 + pc0 * 8);
        uint4 k1 = *(const uint4*)(Ksb + pr1 * 64 + pc1 * 8);
        uint4 v0 = *(const uint4*)(Vsb + (size_t)pr0 * 640 + pc0 * 8);
        uint4 v1 = *(const uint4*)(Vsb + (size_t)pr1 * 640 + pc1 * 8);
        *(uint4*)(&Kl[0][kd0]) = k0;
        *(uint4*)(&Kl[0][kd1]) = k1;
        *(uint4*)(&Vl[0][kd0]) = v0;
        *(uint4*)(&Vl[0][kd1]) = v1;
    }
    __syncthreads();
    int cur = 0;

    for (int kt = 0; kt < 10; ++kt) {
        const bool full = (kt < 9);
        uint4 nk0, nk1, nv0, nv1;
        if (full) {     // issue next tile's loads early (latency hides below)
            const u16* Ks = Ksb + (size_t)(kt + 1) * 64 * 64;
            const u16* Vs = Vsb + (size_t)(kt + 1) * 64;
            nk0 = *(const uint4*)(Ks + pr0 * 64 + pc0 * 8);
            nk1 = *(const uint4*)(Ks + pr1 * 64 + pc1 * 8);
            nv0 = *(const uint4*)(Vs + (size_t)pr0 * 640 + pc0 * 8);
            nv1 = *(const uint4*)(Vs + (size_t)pr1 * 640 + pc1 * 8);
        }
        const u16* Kc = &Kl[cur][0];
        const u16* Vc = &Vl[cur][0];

        // S = Q K^T
        f32x4 sac[4];
#pragma unroll
        for (int cb = 0; cb < 4; ++cb) {
            if (full || cb == 0) {
                const int row = cb * 16 + lr;
                const bf16x8 kb0 = *(const bf16x8*)(Kc + row * 64 + ch0);
                const bf16x8 kb1 = *(const bf16x8*)(Kc + row * 64 + (ch0 ^ 32));
                f32x4 z = {};
                z = mfma16(qa0, kb0, z);
                sac[cb] = mfma16(qa1, kb1, z);
            }
        }

        float s[4][4], tm[4];
#pragma unroll
        for (int r = 0; r < 4; ++r) tm[r] = -3e38f;
#pragma unroll
        for (int cb = 0; cb < 4; ++cb) {
            if (full || cb == 0) {
                const int m = kt * 64 + cb * 16 + lr;
                float ci, cj;
                if (m == 0) { ci = 200.f; cj = 0.f; }
                else {
                    const int mm1 = m - 1;
                    const int pi = mm1 / 24;
                    ci = (float)pi;
                    cj = (float)(mm1 - pi * 24);
                }
#pragma unroll
                for (int r = 0; r < 4; ++r) {
                    const float df = fabsf(gi[r] - ci) + fabsf(gj[r] - cj);
                    const int idx = (int)df;
                    float v = fmaf(sac[cb][r], scale2, lut[idx]);
                    if (!full) v = (lr == 0) ? v : -1e30f;   // pad keys, tail tile
                    s[cb][r] = v;
                    tm[r] = fmaxf(tm[r], v);
                }
            } else {
#pragma unroll
                for (int r = 0; r < 4; ++r) s[cb][r] = -1e30f;
            }
        }
#pragma unroll
        for (int r = 0; r < 4; ++r) tm[r] = dpp_max16(tm[r]);

        float over = tm[0] - M[0];
        over = fmaxf(over, tm[1] - M[1]);
        over = fmaxf(over, tm[2] - M[2]);
        over = fmaxf(over, tm[3] - M[3]);
        if (__any(over > 11.5f)) {
#pragma unroll
            for (int r = 0; r < 4; ++r) {
                const float Mn = fmaxf(M[r], tm[r]);
                const float a = fexp2(M[r] - Mn);
                L[r] *= a;
                acco[0][r] *= a; acco[1][r] *= a;
                acco[2][r] *= a; acco[3][r] *= a;
                M[r] = Mn;
            }
        }

        u16* pw = &Plds[w][0];
#pragma unroll
        for (int cb = 0; cb < 4; ++cb)
#pragma unroll
            for (int r = 0; r < 4; ++r) {
                const float p = fexp2(s[cb][r] - M[r]);
                L[r] += p;
                pw[(4 * lg + r) * 72 + cb * 16 + lr] = f2bf(p);
            }
        const bf16x8 pa0 = *(const bf16x8*)(pw + lr * 72 + lg * 8);
        const bf16x8 pa1 = *(const bf16x8*)(pw + lr * 72 + 32 + lg * 8);
#pragma unroll
        for (int f = 0; f < 4; ++f) {
            const int vrow = f * 16 + lr;
            const bf16x8 vb0 = *(const bf16x8*)(Vc + vrow * 64 + ch0);
            acco[f] = mfma16(pa0, vb0, acco[f]);
            if (full) {
                const bf16x8 vb1 = *(const bf16x8*)(Vc + vrow * 64 + (ch0 ^ 32));
                acco[f] = mfma16(pa1, vb1, acco[f]);
            }
        }

        if (full) {     // land prefetched tile into the other buffer
            __syncthreads();
            *(uint4*)(&Kl[cur ^ 1][kd0]) = nk0;
            *(uint4*)(&Kl[cur ^ 1][kd1]) = nk1;
            *(uint4*)(&Vl[cur ^ 1][kd0]) = nv0;
            *(uint4*)(&Vl[cur ^ 1][kd1]) = nv1;
            __syncthreads();
            cur ^= 1;
        }
    }

    float inv[4];
#pragma unroll
    for (int r = 0; r < 4; ++r) inv[r] = __builtin_amdgcn_rcpf(dpp_sum16(L[r]));
#pragma unroll
    for (int f = 0; f < 4; ++f)
#pragma unroll
        for (int r = 0; r < 4; ++r) {
            const int n = qrow0 + 4 * lg + r;     // <= 575, always valid
            Og[((size_t)b * 577 + n) * 768 + h * 64 + f * 16 + lr] =
                f2bf(acco[f][r] * inv[r]);
        }
}

// ---------------- attention for the single leftover row n=576 ----------------
__launch_bounds__(256)
__global__ void k_attn_last(const u16* __restrict__ Qg, const u16* __restrict__ Kg,
                            const u16* __restrict__ Vtg, const float* __restrict__ coef,
                            u16* __restrict__ Og) {
    const int bh = blockIdx.x;
    const int b = bh / 12, h = bh - b * 12;
    const int t = threadIdx.x;
    const int lane = t & 63, w = t >> 6;
    __shared__ float qs[64];
    __shared__ float ps[640];
    __shared__ float red[4];
    __shared__ float opart[4][64];
    const float l2e = 1.4426950408889634f;
    const float c0 = coef[h * 4 + 0] * l2e, c1 = coef[h * 4 + 1] * l2e,
                c2 = coef[h * 4 + 2] * l2e, c3 = coef[h * 4 + 3] * l2e;
    const float scale2 = 0.125f * l2e;

    if (t < 64) qs[t] = bf2f(Qg[((size_t)bh * 640 + 576) * 64 + t]);
    __syncthreads();

    float sv[3];
#pragma unroll
    for (int u = 0; u < 3; ++u) {
        const int k = t + u * 256;
        float s = -3e38f;
        if (k < 577) {
            const u16* kp = Kg + ((size_t)bh * 640 + k) * 64;
            float acc = 0.f;
            for (int j = 0; j < 64; ++j) acc += qs[j] * bf2f(kp[j]);
            float rv = 0.f;
            if (k >= 1) {
                const int km1 = k - 1;
                const int ki = km1 / 24;
                const float d = fabsf(23.f - (float)ki) + fabsf(23.f - (float)(km1 - ki * 24));
                rv = ((c3 * d + c2) * d + c1) * d + c0;
            }
            s = fmaf(acc, scale2, rv);
        }
        sv[u] = s;
    }
    float v = fmaxf(fmaxf(sv[0], sv[1]), sv[2]);
    v = fmaxf(v, __shfl_xor(v, 1));  v = fmaxf(v, __shfl_xor(v, 2));
    v = fmaxf(v, __shfl_xor(v, 4));  v = fmaxf(v, __shfl_xor(v, 8));
    v = fmaxf(v, __shfl_xor(v, 16)); v = fmaxf(v, __shfl_xor(v, 32));
    if (lane == 0) red[w] = v;
    __syncthreads();
    const float Mx = fmaxf(fmaxf(red[0], red[1]), fmaxf(red[2], red[3]));

    float lsum = 0.f;
#pragma unroll
    for (int u = 0; u < 3; ++u) {
        const int k = t + u * 256;
        const float p = (k < 577) ? fexp2(sv[u] - Mx) : 0.f;
        if (k < 640) ps[k] = p;
        lsum += p;
    }
    lsum += __shfl_xor(lsum, 1);  lsum += __shfl_xor(lsum, 2);
    lsum += __shfl_xor(lsum, 4);  lsum += __shfl_xor(lsum, 8);
    lsum += __shfl_xor(lsum, 16); lsum += __shfl_xor(lsum, 32);
    __syncthreads();
    if (lane == 0) red[w] = lsum;
    __syncthreads();
    const float Lx = red[0] + red[1] + red[2] + red[3];

    const int d = t & 63, qd = t >> 6;
    const u16* vp = Vtg + ((size_t)bh * 64 + d) * 640;
    float o = 0.f;
    for (int k = qd * 160; k < qd * 160 + 160; ++k) o += ps[k] * bf2f(vp[k]);
    opart[qd][d] = o;
    __syncthreads();
    if (t < 64) {
        const float oo = (opart[0][t] + opart[1][t] + opart[2][t] + opart[3][t]) / Lx;
        Og[((size_t)b * 577 + 576) * 768 + h * 64 + t] = f2bf(oo);
    }
}

// ---------------- launch ----------------
extern "C" void kernel_launch(void* const* d_in, const int* in_sizes, int n_in,
                              void* d_out, int out_size, void* d_ws, size_t ws_size,
                              hipStream_t stream) {
    const float* x      = (const float*)d_in[0];
    const float* W_qkv  = (const float*)d_in[1];
    const float* W_proj = (const float*)d_in[2];
    const float* b_proj = (const float*)d_in[3];
    const float* coef   = (const float*)d_in[4];
    float* out = (float*)d_out;
    char* ws = (char*)d_ws;

    u16* xb   = (u16*)(ws + 0);                        // 9232*768*2   = 14,180,352
    u16* Og   = (u16*)(ws + 14180352);                 // 9232*768*2   = 14,180,352
    u16* wqkv = (u16*)(ws + 28360704);                 // 2304*768*2   =  3,538,944
    u16* wprj = (u16*)(ws + 31899648);                 // 768*768*2    =  1,179,648
    u16* Qg   = (u16*)(ws + 33079296);                 // 192*640*64*2 = 15,728,640
    u16* Kg   = (u16*)(ws + 48807936);                 // 192*640*64*2 = 15,728,640
    u16* Vtg  = (u16*)(ws + 64536576);                 // 192*64*640*2 = 15,728,640

    hipMemsetAsync(Vtg, 0, 15728640, stream);          // pad keys -> 0

    k_prep<<<2048, 256, 0, stream>>>(x, W_qkv, W_proj, xb, wqkv, wprj);

    k_gemm<0><<<dim3(18, 73), 256, 0, stream>>>(xb, wqkv, Qg, Kg, Vtg,
                                                nullptr, nullptr);
    k_attn<<<dim3(192, 9), 256, 0, stream>>>(Qg, Kg, Vtg, coef, Og);
    k_attn_last<<<192, 256, 0, stream>>>(Qg, Kg, Vtg, coef, Og);
    k_gemm<1><<<dim3(6, 73), 256, 0, stream>>>(Og, wprj, nullptr, nullptr,
                                               nullptr, out, b_proj);
}